// Round 1
// baseline (1752.208 us; speedup 1.0000x reference)
//
#include <hip/hip_runtime.h>
#include <math.h>

// Problem constants (CollaborativeRNNModel): B=32, S=128, U=256, H=128, V=30001
#define B_    32
#define S_    128
#define U_    256
#define H_    128
#define H2_   256
#define V_    30001
#define ROWS_ 4096   // B_*S_

// ---------------------------------------------------------------------------
// Kernel 1: per-batch GRU-like recurrence. One block per batch element (the
// 32 chains are independent: state[b,u] only touched by batch b).
// Whole per-batch state (256x128 fp32 = 128 KiB) lives in LDS.
// Writes activations TRANSPOSED: At[j][b*S+t]  (k-major for the GEMM A-load).
// ---------------------------------------------------------------------------
__global__ __launch_bounds__(256) void rnn_kernel(
    const int*   __restrict__ users, const int* __restrict__ items,
    const float* __restrict__ h0,
    const float* __restrict__ P_ru, const float* __restrict__ W_ru,
    const float* __restrict__ b_ru,
    const float* __restrict__ P_c,  const float* __restrict__ W_c,
    const float* __restrict__ b_c,
    float* __restrict__ At)          // [H_][ROWS_]
{
    __shared__ float state[U_ * H_];   // 128 KiB
    __shared__ float rbuf[H_];         // r * h_prev (pre-multiplied)
    __shared__ float zbuf[H_];
    __shared__ int   us[S_];
    __shared__ int   is[S_];

    const int b   = blockIdx.x;
    const int tid = threadIdx.x;

    // init state from h0 (coalesced float4 copy: 32768 floats)
    {
        const float4* src = (const float4*)(h0 + (size_t)b * U_ * H_);
        float4*       dst = (float4*)state;
        #pragma unroll
        for (int i = 0; i < (U_ * H_ / 4) / 256; ++i)
            dst[i * 256 + tid] = src[i * 256 + tid];
    }
    if (tid < S_) {
        us[tid] = users[b * S_ + tid];
        is[tid] = items[b * S_ + tid];
    }
    const float brj = b_ru[tid];                      // per-thread bias, loop-invariant
    const float bcj = (tid < H_) ? b_c[tid] : 0.f;
    __syncthreads();

    for (int t = 0; t < S_; ++t) {
        const int u  = us[t];
        const int it = is[t];
        const float* hrow = state + u * H_;           // LDS, h_prev

        // issue the P_ru load early; consumed after the matvec loop
        const float p = P_ru[(size_t)it * H2_ + tid];

        // Phase A: thread j computes ru[j], j in 0..255
        float acc = 0.f;
        const float* wcol = W_ru + tid;               // column j of W_ru (L2-resident)
        #pragma unroll 8
        for (int k4 = 0; k4 < H_; k4 += 4) {
            const float4 hv = *((const float4*)(hrow + k4));   // broadcast LDS read
            acc = fmaf(hv.x, wcol[(k4 + 0) * H2_], acc);
            acc = fmaf(hv.y, wcol[(k4 + 1) * H2_], acc);
            acc = fmaf(hv.z, wcol[(k4 + 2) * H2_], acc);
            acc = fmaf(hv.w, wcol[(k4 + 3) * H2_], acc);
        }
        acc += p + brj;
        const float sg = 1.f / (1.f + expf(-acc));    // sigmoid
        if (tid < H_) rbuf[tid] = sg * hrow[tid];     // r*h_prev, premultiplied
        else          zbuf[tid - H_] = sg;            // z
        __syncthreads();

        // Phase B: thread j < 128 computes c[j], h_new[j]
        if (tid < H_) {
            const float pc = P_c[(size_t)it * H_ + tid];
            float acc2 = 0.f;
            const float* wccol = W_c + tid;
            #pragma unroll 8
            for (int k4 = 0; k4 < H_; k4 += 4) {
                const float4 rv = *((const float4*)(rbuf + k4));
                acc2 = fmaf(rv.x, wccol[(k4 + 0) * H_], acc2);
                acc2 = fmaf(rv.y, wccol[(k4 + 1) * H_], acc2);
                acc2 = fmaf(rv.z, wccol[(k4 + 2) * H_], acc2);
                acc2 = fmaf(rv.w, wccol[(k4 + 3) * H_], acc2);
            }
            acc2 += pc + bcj;
            const float c  = tanhf(acc2);
            const float z  = zbuf[tid];
            const float hp = hrow[tid];
            const float hn = fmaf(z, hp - c, c);      // z*hp + (1-z)*c
            state[u * H_ + tid] = hn;
            At[(size_t)tid * ROWS_ + b * S_ + t] = hn;
        }
        __syncthreads();
    }
}

// ---------------------------------------------------------------------------
// Kernel 2: logits = A[4096,128] @ ws[128,30001], fp32 vector GEMM.
// 128x128 C-tile per block, K=128 consumed in one shot (no k-outer loop).
// Both LDS tiles k-major -> straight coalesced global loads, conflict-free
// LDS writes. 8x8 micro-tile as 2x2 groups of 4x4 (col groups tx*4 and
// 64+tx*4) -> float4 LDS reads are <=2-way bank aliased (free).
// ---------------------------------------------------------------------------
#define OUTER(cc, av, bv)                     \
    cc.x = fmaf(av, bv.x, cc.x);              \
    cc.y = fmaf(av, bv.y, cc.y);              \
    cc.z = fmaf(av, bv.z, cc.z);              \
    cc.w = fmaf(av, bv.w, cc.w);

__global__ __launch_bounds__(256) void gemm_kernel(
    const float* __restrict__ At,    // [H_][ROWS_]  (k-major)
    const float* __restrict__ wsm,   // [H_][V_]     (k-major)
    float* __restrict__ out)         // [ROWS_][V_]
{
    __shared__ float As[H_ * 128];   // [k][row] 64 KiB
    __shared__ float Bs[H_ * 128];   // [k][col] 64 KiB

    const int rb  = blockIdx.x * 128;   // 32 row tiles
    const int cb  = blockIdx.y * 128;   // 235 col tiles
    const int tid = threadIdx.x;

    #pragma unroll
    for (int i = 0; i < 64; ++i) {
        const int flat = i * 256 + tid;
        const int k = flat >> 7;
        const int r = flat & 127;
        As[flat] = At[(size_t)k * ROWS_ + rb + r];
    }
    #pragma unroll
    for (int i = 0; i < 64; ++i) {
        const int flat = i * 256 + tid;
        const int k = flat >> 7;
        const int c = flat & 127;
        const int col = cb + c;
        Bs[flat] = (col < V_) ? wsm[(size_t)k * V_ + col] : 0.f;
    }
    __syncthreads();

    const int tx = tid & 15;
    const int ty = tid >> 4;

    float4 c00[4], c01[4], c10[4], c11[4];
    #pragma unroll
    for (int i = 0; i < 4; ++i) {
        c00[i] = make_float4(0.f, 0.f, 0.f, 0.f);
        c01[i] = make_float4(0.f, 0.f, 0.f, 0.f);
        c10[i] = make_float4(0.f, 0.f, 0.f, 0.f);
        c11[i] = make_float4(0.f, 0.f, 0.f, 0.f);
    }

    const float4* As4 = (const float4*)As;
    const float4* Bs4 = (const float4*)Bs;

    #pragma unroll 4
    for (int k = 0; k < H_; ++k) {
        const float4 a0 = As4[k * 32 + ty];        // rows ty*4   .. +3
        const float4 a1 = As4[k * 32 + 16 + ty];   // rows 64+ty*4.. +3
        const float4 b0 = Bs4[k * 32 + tx];        // cols tx*4   .. +3
        const float4 b1 = Bs4[k * 32 + 16 + tx];   // cols 64+tx*4.. +3
        OUTER(c00[0], a0.x, b0) OUTER(c00[1], a0.y, b0)
        OUTER(c00[2], a0.z, b0) OUTER(c00[3], a0.w, b0)
        OUTER(c01[0], a0.x, b1) OUTER(c01[1], a0.y, b1)
        OUTER(c01[2], a0.z, b1) OUTER(c01[3], a0.w, b1)
        OUTER(c10[0], a1.x, b0) OUTER(c10[1], a1.y, b0)
        OUTER(c10[2], a1.z, b0) OUTER(c10[3], a1.w, b0)
        OUTER(c11[0], a1.x, b1) OUTER(c11[1], a1.y, b1)
        OUTER(c11[2], a1.z, b1) OUTER(c11[3], a1.w, b1)
    }

    // Epilogue: V_=30001 is odd -> rows are not 16B aligned, scalar dword
    // stores (still line-coalesced across the 16 tx lanes).
    const bool full = (cb + 128 <= V_);
    #pragma unroll
    for (int i = 0; i < 4; ++i) {
        const int r1 = rb + ty * 4 + i;
        float* o1 = out + (size_t)r1 * V_ + cb;
        float* o2 = out + (size_t)(r1 + 64) * V_ + cb;
        const int cA = tx * 4;
        const int cB = 64 + tx * 4;
        if (full) {
            o1[cA + 0] = c00[i].x; o1[cA + 1] = c00[i].y;
            o1[cA + 2] = c00[i].z; o1[cA + 3] = c00[i].w;
            o1[cB + 0] = c01[i].x; o1[cB + 1] = c01[i].y;
            o1[cB + 2] = c01[i].z; o1[cB + 3] = c01[i].w;
            o2[cA + 0] = c10[i].x; o2[cA + 1] = c10[i].y;
            o2[cA + 2] = c10[i].z; o2[cA + 3] = c10[i].w;
            o2[cB + 0] = c11[i].x; o2[cB + 1] = c11[i].y;
            o2[cB + 2] = c11[i].z; o2[cB + 3] = c11[i].w;
        } else {
            const float vA1[4] = {c00[i].x, c00[i].y, c00[i].z, c00[i].w};
            const float vB1[4] = {c01[i].x, c01[i].y, c01[i].z, c01[i].w};
            const float vA2[4] = {c10[i].x, c10[i].y, c10[i].z, c10[i].w};
            const float vB2[4] = {c11[i].x, c11[i].y, c11[i].z, c11[i].w};
            #pragma unroll
            for (int j = 0; j < 4; ++j) {
                if (cb + cA + j < V_) { o1[cA + j] = vA1[j]; o2[cA + j] = vA2[j]; }
                if (cb + cB + j < V_) { o1[cB + j] = vB1[j]; o2[cB + j] = vB2[j]; }
            }
        }
    }
}

extern "C" void kernel_launch(void* const* d_in, const int* in_sizes, int n_in,
                              void* d_out, int out_size, void* d_ws, size_t ws_size,
                              hipStream_t stream) {
    const int*   users = (const int*)  d_in[0];
    const int*   items = (const int*)  d_in[1];
    const float* h0    = (const float*)d_in[2];
    const float* P_ru  = (const float*)d_in[3];
    const float* W_ru  = (const float*)d_in[4];
    const float* b_ru  = (const float*)d_in[5];
    const float* P_c   = (const float*)d_in[6];
    const float* W_c   = (const float*)d_in[7];
    const float* b_c   = (const float*)d_in[8];
    const float* wsm   = (const float*)d_in[9];
    float* out = (float*)d_out;
    float* At  = (float*)d_ws;          // [H_][ROWS_] = 2 MiB scratch

    rnn_kernel<<<B_, 256, 0, stream>>>(users, items, h0, P_ru, W_ru, b_ru,
                                       P_c, W_c, b_c, At);
    gemm_kernel<<<dim3(32, (V_ + 127) / 128), 256, 0, stream>>>(At, wsm, out);
}